// Round 1
// baseline (552.443 us; speedup 1.0000x reference)
//
#include <hip/hip_runtime.h>
#include <math.h>

// B=128, E=8, D=512, H=2048. 64 pairs (a,e).
// Pass1: h[p] = gelu(feat[:,a] @ W1[p] + b1[p])   [128 x 2048] bf16 -> ws
// Pass2: out = h[p] @ W2[p] + b2[p]; accumulate (out - tgt)^2 -> partials
// Pass3: scalar = sum(partials) / (128*512*8)

typedef float floatx4 __attribute__((ext_vector_type(4)));
typedef __bf16 bf16x8 __attribute__((ext_vector_type(8)));
typedef unsigned short ushortx8 __attribute__((ext_vector_type(8)));
typedef unsigned short ushortx4 __attribute__((ext_vector_type(4)));

__device__ __forceinline__ unsigned short f2bf(float f) {
    unsigned u = __builtin_bit_cast(unsigned, f);
    u += 0x7fffu + ((u >> 16) & 1u);   // RNE
    return (unsigned short)(u >> 16);
}

// LDS row stride: 40 shorts = 80 B (16B-aligned, breaks pow2 bank pattern)
#define LDSTR 40

// ---------------------------------------------------------------- pass 1
__global__ __launch_bounds__(256, 2) void k_gemm1(
    const float* __restrict__ feat, const float* __restrict__ W1,
    const float* __restrict__ b1, unsigned short* __restrict__ hbuf)
{
    __shared__ __align__(16) unsigned short lA[128 * LDSTR];
    __shared__ __align__(16) unsigned short lB[128 * LDSTR];

    const int bi = blockIdx.x;
    const int xcd = bi & 7, slot = bi >> 3;
    const int pair = xcd * 8 + (slot >> 4);   // all 8 pairs of one 'a' share an XCD
    const int nt   = slot & 15;               // 16 N-tiles of 128 over H=2048
    const int a    = pair >> 3;
    const int t = threadIdx.x;
    const int w = t >> 6, l = t & 63;
    const int lr = l & 15, lq = l >> 4;
    const int n_base = nt * 128;

    const float* Bp = W1 + (size_t)pair * 512 * 2048 + n_base;
    const int ar = t >> 3;          // A rows 0..31 (+32*s)
    const int ac = (t & 7) * 4;     // A k within 32 (floats)
    const int bk0 = w * 8;          // B k0 within step

    floatx4 apf[4];
    float bpf[16];

    auto loadA = [&](int kb) {
        #pragma unroll
        for (int s = 0; s < 4; ++s) {
            const float* p = feat + ((size_t)((ar + 32 * s) * 8 + a)) * 512 + kb + ac;
            apf[s] = *(const floatx4*)p;
        }
    };
    auto loadB = [&](int kb) {
        #pragma unroll
        for (int rep = 0; rep < 2; ++rep)
            #pragma unroll
            for (int jj = 0; jj < 8; ++jj)
                bpf[rep * 8 + jj] = Bp[(size_t)(kb + bk0 + jj) * 2048 + rep * 64 + l];
    };
    auto stage = [&]() {
        #pragma unroll
        for (int s = 0; s < 4; ++s) {
            ushortx4 v = { f2bf(apf[s][0]), f2bf(apf[s][1]),
                           f2bf(apf[s][2]), f2bf(apf[s][3]) };
            *(ushortx4*)&lA[(ar + 32 * s) * LDSTR + ac] = v;
        }
        #pragma unroll
        for (int rep = 0; rep < 2; ++rep) {
            ushortx8 v;
            #pragma unroll
            for (int jj = 0; jj < 8; ++jj) v[jj] = f2bf(bpf[rep * 8 + jj]);
            *(ushortx8*)&lB[(rep * 64 + l) * LDSTR + bk0] = v;
        }
    };

    const int m0 = (w & 1) * 64;
    const int n0 = (w >> 1) * 64;
    floatx4 acc[4][4];
    const floatx4 zero = {0.f, 0.f, 0.f, 0.f};
    #pragma unroll
    for (int i = 0; i < 4; ++i)
        #pragma unroll
        for (int j = 0; j < 4; ++j) acc[i][j] = zero;

    loadA(0); loadB(0);
    for (int kt = 0; kt < 16; ++kt) {
        __syncthreads();
        stage();
        __syncthreads();
        if (kt + 1 < 16) { loadA((kt + 1) * 32); loadB((kt + 1) * 32); }
        bf16x8 af[4], bv[4];
        #pragma unroll
        for (int i = 0; i < 4; ++i)
            af[i] = __builtin_bit_cast(bf16x8,
                *(const ushortx8*)&lA[(m0 + 16 * i + lr) * LDSTR + lq * 8]);
        #pragma unroll
        for (int j = 0; j < 4; ++j)
            bv[j] = __builtin_bit_cast(bf16x8,
                *(const ushortx8*)&lB[(n0 + 16 * j + lr) * LDSTR + lq * 8]);
        #pragma unroll
        for (int i = 0; i < 4; ++i)
            #pragma unroll
            for (int j = 0; j < 4; ++j)
                acc[i][j] = __builtin_amdgcn_mfma_f32_16x16x32_bf16(
                    af[i], bv[j], acc[i][j], 0, 0, 0);
    }

    // epilogue: +b1, exact gelu, store bf16 h in [pair][kchunk][row][32] blocks
    #pragma unroll
    for (int j = 0; j < 4; ++j) {
        const int col = n_base + n0 + 16 * j + lr;
        const float bias = b1[pair * 2048 + col];
        const size_t cbase = ((size_t)pair * 64 + (col >> 5)) * 128;
        const int cw = col & 31;
        #pragma unroll
        for (int i = 0; i < 4; ++i)
            #pragma unroll
            for (int r = 0; r < 4; ++r) {
                const int row = m0 + 16 * i + lq * 4 + r;
                float x = acc[i][j][r] + bias;
                float g = 0.5f * x * (1.0f + erff(x * 0.70710678118654752f));
                hbuf[(cbase + row) * 32 + cw] = f2bf(g);
            }
    }
}

// ---------------------------------------------------------------- pass 2
__global__ __launch_bounds__(256, 2) void k_gemm2(
    const unsigned short* __restrict__ hbuf, const float* __restrict__ W2,
    const float* __restrict__ b2, const float* __restrict__ tgt,
    float* __restrict__ partials)
{
    __shared__ __align__(16) unsigned short lA[128 * LDSTR];
    __shared__ __align__(16) unsigned short lB[128 * LDSTR];
    __shared__ float red[4];

    const int bi = blockIdx.x;
    const int xcd = bi & 7, slot = bi >> 3;
    const int pair = xcd * 8 + (slot >> 2);
    const int nt   = slot & 3;                // 4 N-tiles of 128 over D=512
    const int a    = pair >> 3;
    const int t = threadIdx.x;
    const int w = t >> 6, l = t & 63;
    const int lr = l & 15, lq = l >> 4;
    const int n_base = nt * 128;

    const float* Bp = W2 + (size_t)pair * 2048 * 512 + n_base;
    const unsigned short* Ap = hbuf + (size_t)pair * 64 * 4096 + t * 16;
    const int bk0 = w * 8;

    ushortx8 apf[2];
    float bpf[16];

    auto loadA = [&](int kt) {
        const unsigned short* p = Ap + (size_t)kt * 4096;
        apf[0] = *(const ushortx8*)p;
        apf[1] = *(const ushortx8*)(p + 8);
    };
    auto loadB = [&](int kb) {
        #pragma unroll
        for (int rep = 0; rep < 2; ++rep)
            #pragma unroll
            for (int jj = 0; jj < 8; ++jj)
                bpf[rep * 8 + jj] = Bp[(size_t)(kb + bk0 + jj) * 512 + rep * 64 + l];
    };
    auto stage = [&]() {
        *(ushortx8*)&lA[(t >> 1) * LDSTR + (t & 1) * 16] = apf[0];
        *(ushortx8*)&lA[(t >> 1) * LDSTR + (t & 1) * 16 + 8] = apf[1];
        #pragma unroll
        for (int rep = 0; rep < 2; ++rep) {
            ushortx8 v;
            #pragma unroll
            for (int jj = 0; jj < 8; ++jj) v[jj] = f2bf(bpf[rep * 8 + jj]);
            *(ushortx8*)&lB[(rep * 64 + l) * LDSTR + bk0] = v;
        }
    };

    const int m0 = (w & 1) * 64;
    const int n0 = (w >> 1) * 64;
    floatx4 acc[4][4];
    const floatx4 zero = {0.f, 0.f, 0.f, 0.f};
    #pragma unroll
    for (int i = 0; i < 4; ++i)
        #pragma unroll
        for (int j = 0; j < 4; ++j) acc[i][j] = zero;

    loadA(0); loadB(0);
    for (int kt = 0; kt < 64; ++kt) {
        __syncthreads();
        stage();
        __syncthreads();
        if (kt + 1 < 64) { loadA(kt + 1); loadB((kt + 1) * 32); }
        bf16x8 af[4], bv[4];
        #pragma unroll
        for (int i = 0; i < 4; ++i)
            af[i] = __builtin_bit_cast(bf16x8,
                *(const ushortx8*)&lA[(m0 + 16 * i + lr) * LDSTR + lq * 8]);
        #pragma unroll
        for (int j = 0; j < 4; ++j)
            bv[j] = __builtin_bit_cast(bf16x8,
                *(const ushortx8*)&lB[(n0 + 16 * j + lr) * LDSTR + lq * 8]);
        #pragma unroll
        for (int i = 0; i < 4; ++i)
            #pragma unroll
            for (int j = 0; j < 4; ++j)
                acc[i][j] = __builtin_amdgcn_mfma_f32_16x16x32_bf16(
                    af[i], bv[j], acc[i][j], 0, 0, 0);
    }

    // epilogue: squared-error accumulation
    float lsum = 0.f;
    #pragma unroll
    for (int j = 0; j < 4; ++j) {
        const int col = n_base + n0 + 16 * j + lr;
        const float bias = b2[pair * 512 + col];
        #pragma unroll
        for (int i = 0; i < 4; ++i)
            #pragma unroll
            for (int r = 0; r < 4; ++r) {
                const int row = m0 + 16 * i + lq * 4 + r;
                float e = acc[i][j][r] + bias - tgt[((size_t)row * 8 + a) * 512 + col];
                lsum += e * e;
            }
    }
    #pragma unroll
    for (int off = 32; off > 0; off >>= 1) lsum += __shfl_down(lsum, off, 64);
    if (l == 0) red[w] = lsum;
    __syncthreads();
    if (t == 0) partials[bi] = red[0] + red[1] + red[2] + red[3];
}

// ---------------------------------------------------------------- pass 3
__global__ void k_reduce(const float* __restrict__ partials, float* __restrict__ out)
{
    const int t = threadIdx.x;
    float v = partials[t];
    #pragma unroll
    for (int off = 32; off > 0; off >>= 1) v += __shfl_down(v, off, 64);
    __shared__ float red[4];
    if ((t & 63) == 0) red[t >> 6] = v;
    __syncthreads();
    if (t == 0)
        out[0] = (red[0] + red[1] + red[2] + red[3]) * (1.0f / 524288.0f); // /(B*D)/E
}

extern "C" void kernel_launch(void* const* d_in, const int* in_sizes, int n_in,
                              void* d_out, int out_size, void* d_ws, size_t ws_size,
                              hipStream_t stream) {
    const float* feat = (const float*)d_in[0];
    const float* tgt  = (const float*)d_in[1];
    const float* W1   = (const float*)d_in[2];
    const float* b1   = (const float*)d_in[3];
    const float* W2   = (const float*)d_in[4];
    const float* b2   = (const float*)d_in[5];

    unsigned short* hbuf = (unsigned short*)d_ws;                 // 32 MiB bf16 h
    float* partials = (float*)((char*)d_ws + (size_t)33554432);   // 256 floats
    float* out = (float*)d_out;

    k_gemm1<<<dim3(1024), dim3(256), 0, stream>>>(feat, W1, b1, hbuf);
    k_gemm2<<<dim3(256),  dim3(256), 0, stream>>>(hbuf, W2, b2, tgt, partials);
    k_reduce<<<dim3(1),   dim3(256), 0, stream>>>(partials, out);
}

// Round 3
// 549.459 us; speedup vs baseline: 1.0054x; 1.0054x over previous
//
#include <hip/hip_runtime.h>
#include <math.h>

// B=128, E=8, D=512, H=2048. 64 pairs (a,e).
// Pass1: h[p] = gelu(feat[:,a] @ W1[p] + b1[p])   [128 x 2048] bf16 -> ws
// Pass2: out = h[p] @ W2[p] + b2[p]; accumulate (out - tgt)^2 -> partials
// Pass3: scalar = sum(partials) / (128*512*8)

typedef float floatx4 __attribute__((ext_vector_type(4)));
typedef __bf16 bf16x8 __attribute__((ext_vector_type(8)));
typedef unsigned short ushortx8 __attribute__((ext_vector_type(8)));
typedef unsigned short ushortx4 __attribute__((ext_vector_type(4)));

__device__ __forceinline__ unsigned short f2bf(float f) {
    unsigned u = __builtin_bit_cast(unsigned, f);
    u += 0x7fffu + ((u >> 16) & 1u);   // RNE
    return (unsigned short)(u >> 16);
}

// LDS row stride: 40 shorts = 80 B (16B-aligned, breaks pow2 bank pattern)
#define LDSTR 40

// ---------------------------------------------------------------- pass 1
// 1024 blocks: 64 pairs x 16 n-tiles of 128 over H=2048. 3 blocks/CU.
__global__ __launch_bounds__(256, 3) void k_gemm1(
    const float* __restrict__ feat, const float* __restrict__ W1,
    const float* __restrict__ b1, unsigned short* __restrict__ hbuf)
{
    __shared__ __align__(16) unsigned short lA[128 * LDSTR];
    __shared__ __align__(16) unsigned short lB[128 * LDSTR];

    const int bi = blockIdx.x;
    const int xcd = bi & 7, slot = bi >> 3;
    const int pair = xcd * 8 + (slot >> 4);   // all 8 pairs of one 'a' share an XCD
    const int nt   = slot & 15;               // 16 N-tiles of 128 over H=2048
    const int a    = pair >> 3;
    const int t = threadIdx.x;
    const int w = t >> 6, l = t & 63;
    const int lr = l & 15, lq = l >> 4;
    const int n_base = nt * 128;

    const float* Bp = W1 + (size_t)pair * 512 * 2048 + n_base;
    const int ar = t >> 3;          // A rows 0..31 (+32*s)
    const int ac = (t & 7) * 4;     // A k within 32 (floats)
    const int bk0 = w * 8;          // B k0 within step

    floatx4 apf[4];
    float bpf[16];

    auto loadA = [&](int kb) {
        #pragma unroll
        for (int s = 0; s < 4; ++s) {
            const float* p = feat + ((size_t)((ar + 32 * s) * 8 + a)) * 512 + kb + ac;
            apf[s] = *(const floatx4*)p;
        }
    };
    auto loadB = [&](int kb) {
        #pragma unroll
        for (int rep = 0; rep < 2; ++rep)
            #pragma unroll
            for (int jj = 0; jj < 8; ++jj)
                bpf[rep * 8 + jj] = Bp[(size_t)(kb + bk0 + jj) * 2048 + rep * 64 + l];
    };
    auto stage = [&]() {
        #pragma unroll
        for (int s = 0; s < 4; ++s) {
            ushortx4 v = { f2bf(apf[s][0]), f2bf(apf[s][1]),
                           f2bf(apf[s][2]), f2bf(apf[s][3]) };
            *(ushortx4*)&lA[(ar + 32 * s) * LDSTR + ac] = v;
        }
        #pragma unroll
        for (int rep = 0; rep < 2; ++rep) {
            ushortx8 v;
            #pragma unroll
            for (int jj = 0; jj < 8; ++jj) v[jj] = f2bf(bpf[rep * 8 + jj]);
            *(ushortx8*)&lB[(rep * 64 + l) * LDSTR + bk0] = v;
        }
    };

    const int m0 = (w & 1) * 64;
    const int n0 = (w >> 1) * 64;
    floatx4 acc[4][4];
    const floatx4 zero = {0.f, 0.f, 0.f, 0.f};
    #pragma unroll
    for (int i = 0; i < 4; ++i)
        #pragma unroll
        for (int j = 0; j < 4; ++j) acc[i][j] = zero;

    loadA(0); loadB(0);
    for (int kt = 0; kt < 16; ++kt) {
        __syncthreads();
        stage();
        __syncthreads();
        if (kt + 1 < 16) { loadA((kt + 1) * 32); loadB((kt + 1) * 32); }
        bf16x8 af[4], bv[4];
        #pragma unroll
        for (int i = 0; i < 4; ++i)
            af[i] = __builtin_bit_cast(bf16x8,
                *(const ushortx8*)&lA[(m0 + 16 * i + lr) * LDSTR + lq * 8]);
        #pragma unroll
        for (int j = 0; j < 4; ++j)
            bv[j] = __builtin_bit_cast(bf16x8,
                *(const ushortx8*)&lB[(n0 + 16 * j + lr) * LDSTR + lq * 8]);
        #pragma unroll
        for (int i = 0; i < 4; ++i)
            #pragma unroll
            for (int j = 0; j < 4; ++j)
                acc[i][j] = __builtin_amdgcn_mfma_f32_16x16x32_bf16(
                    af[i], bv[j], acc[i][j], 0, 0, 0);
    }

    // epilogue: +b1, exact gelu, store bf16 h in [pair][kchunk][row][32] blocks
    #pragma unroll
    for (int j = 0; j < 4; ++j) {
        const int col = n_base + n0 + 16 * j + lr;
        const float bias = b1[pair * 2048 + col];
        const size_t cbase = ((size_t)pair * 64 + (col >> 5)) * 128;
        const int cw = col & 31;
        #pragma unroll
        for (int i = 0; i < 4; ++i)
            #pragma unroll
            for (int r = 0; r < 4; ++r) {
                const int row = m0 + 16 * i + lq * 4 + r;
                float x = acc[i][j][r] + bias;
                float g = 0.5f * x * (1.0f + erff(x * 0.70710678118654752f));
                hbuf[(cbase + row) * 32 + cw] = f2bf(g);
            }
    }
}

// ---------------------------------------------------------------- pass 2
// 512 blocks: 64 pairs x 8 n-tiles of 64 over D=512. 2 blocks/CU.
// Tile 128m x 64n; wave tile 64x32 (acc 4x2).
__global__ __launch_bounds__(256, 2) void k_gemm2(
    const unsigned short* __restrict__ hbuf, const float* __restrict__ W2,
    const float* __restrict__ b2, const float* __restrict__ tgt,
    float* __restrict__ partials)
{
    __shared__ __align__(16) unsigned short lA[128 * LDSTR];
    __shared__ __align__(16) unsigned short lB[64 * LDSTR];
    __shared__ float red[4];

    const int bi = blockIdx.x;
    const int xcd = bi & 7, slot = bi >> 3;   // slot 0..63
    const int pair = xcd * 8 + (slot >> 3);
    const int nt   = slot & 7;                // 8 N-tiles of 64 over D=512
    const int a    = pair >> 3;
    const int t = threadIdx.x;
    const int w = t >> 6, l = t & 63;
    const int lr = l & 15, lq = l >> 4;
    const int n_base = nt * 64;

    const float* Bp = W2 + (size_t)pair * 2048 * 512 + n_base;
    const unsigned short* Ap = hbuf + (size_t)pair * 64 * 4096 + t * 16;
    const int bk0 = w * 8;                    // each wave stages 8 k-rows

    ushortx8 apf[2];
    float bpf[8];

    auto loadA = [&](int kt) {
        const unsigned short* p = Ap + (size_t)kt * 4096;
        apf[0] = *(const ushortx8*)p;
        apf[1] = *(const ushortx8*)(p + 8);
    };
    auto loadB = [&](int kb) {
        #pragma unroll
        for (int jj = 0; jj < 8; ++jj)
            bpf[jj] = Bp[(size_t)(kb + bk0 + jj) * 512 + l];
    };
    auto stage = [&]() {
        *(ushortx8*)&lA[(t >> 1) * LDSTR + (t & 1) * 16] = apf[0];
        *(ushortx8*)&lA[(t >> 1) * LDSTR + (t & 1) * 16 + 8] = apf[1];
        ushortx8 v;
        #pragma unroll
        for (int jj = 0; jj < 8; ++jj) v[jj] = f2bf(bpf[jj]);
        *(ushortx8*)&lB[l * LDSTR + bk0] = v;
    };

    const int m0 = (w & 1) * 64;
    const int n0 = (w >> 1) * 32;
    floatx4 acc[4][2];
    const floatx4 zero = {0.f, 0.f, 0.f, 0.f};
    #pragma unroll
    for (int i = 0; i < 4; ++i)
        #pragma unroll
        for (int j = 0; j < 2; ++j) acc[i][j] = zero;

    loadA(0); loadB(0);
    for (int kt = 0; kt < 64; ++kt) {
        __syncthreads();
        stage();
        __syncthreads();
        if (kt + 1 < 64) { loadA(kt + 1); loadB((kt + 1) * 32); }
        bf16x8 af[4], bv[2];
        #pragma unroll
        for (int i = 0; i < 4; ++i)
            af[i] = __builtin_bit_cast(bf16x8,
                *(const ushortx8*)&lA[(m0 + 16 * i + lr) * LDSTR + lq * 8]);
        #pragma unroll
        for (int j = 0; j < 2; ++j)
            bv[j] = __builtin_bit_cast(bf16x8,
                *(const ushortx8*)&lB[(n0 + 16 * j + lr) * LDSTR + lq * 8]);
        #pragma unroll
        for (int i = 0; i < 4; ++i)
            #pragma unroll
            for (int j = 0; j < 2; ++j)
                acc[i][j] = __builtin_amdgcn_mfma_f32_16x16x32_bf16(
                    af[i], bv[j], acc[i][j], 0, 0, 0);
    }

    // epilogue: squared-error accumulation
    float lsum = 0.f;
    #pragma unroll
    for (int j = 0; j < 2; ++j) {
        const int col = n_base + n0 + 16 * j + lr;
        const float bias = b2[pair * 512 + col];
        #pragma unroll
        for (int i = 0; i < 4; ++i)
            #pragma unroll
            for (int r = 0; r < 4; ++r) {
                const int row = m0 + 16 * i + lq * 4 + r;
                float e = acc[i][j][r] + bias - tgt[((size_t)row * 8 + a) * 512 + col];
                lsum += e * e;
            }
    }
    #pragma unroll
    for (int off = 32; off > 0; off >>= 1) lsum += __shfl_down(lsum, off, 64);
    if (l == 0) red[w] = lsum;
    __syncthreads();
    if (t == 0) partials[bi] = red[0] + red[1] + red[2] + red[3];
}

// ---------------------------------------------------------------- pass 3
__global__ void k_reduce(const float* __restrict__ partials, float* __restrict__ out)
{
    const int t = threadIdx.x;   // 512 threads
    float v = partials[t];
    #pragma unroll
    for (int off = 32; off > 0; off >>= 1) v += __shfl_down(v, off, 64);
    __shared__ float red[8];
    if ((t & 63) == 0) red[t >> 6] = v;
    __syncthreads();
    if (t == 0) {
        float s = 0.f;
        #pragma unroll
        for (int i = 0; i < 8; ++i) s += red[i];
        out[0] = s * (1.0f / 524288.0f); // /(B*D)/E
    }
}

extern "C" void kernel_launch(void* const* d_in, const int* in_sizes, int n_in,
                              void* d_out, int out_size, void* d_ws, size_t ws_size,
                              hipStream_t stream) {
    const float* feat = (const float*)d_in[0];
    const float* tgt  = (const float*)d_in[1];
    const float* W1   = (const float*)d_in[2];
    const float* b1   = (const float*)d_in[3];
    const float* W2   = (const float*)d_in[4];
    const float* b2   = (const float*)d_in[5];

    unsigned short* hbuf = (unsigned short*)d_ws;                 // 16 MiB bf16 h
    float* partials = (float*)((char*)d_ws + (size_t)33554432);   // 512 floats
    float* out = (float*)d_out;

    k_gemm1<<<dim3(1024), dim3(256), 0, stream>>>(feat, W1, b1, hbuf);
    k_gemm2<<<dim3(512),  dim3(256), 0, stream>>>(hbuf, W2, b2, tgt, partials);
    k_reduce<<<dim3(1),   dim3(512), 0, stream>>>(partials, out);
}